// Round 5
// baseline (2539.482 us; speedup 1.0000x reference)
//
#include <hip/hip_runtime.h>

// ---------------------------------------------------------------------------
// Dims (fixed by the reference)
// ---------------------------------------------------------------------------
#define Bv 16
#define Kv 12
#define Lv 8
#define Pv 24
#define Dv 768
#define H1v 384
#define Vv 44
#define KLv 96          // K*L
#define N1v 1536        // B*K*L
#define BKv 192         // B*K
#define G1v 2304        // 3*D
#define G2v 1152        // 3*H1
#define G3v 1536        // 4*H1

typedef __bf16 bf16_t;
typedef __attribute__((ext_vector_type(8))) __bf16 bf16x8;
typedef __attribute__((ext_vector_type(4))) float f32x4;

__device__ __forceinline__ float sigmf(float x){ return 1.0f/(1.0f + __expf(-x)); }
__device__ __forceinline__ float tanhft(float x){ float e = __expf(2.f*x); return 1.f - 2.f/(e+1.f); }

// async global->LDS, 16B per lane. LDS dest linear: base + idx*16.
__device__ __forceinline__ void gld_lds16(const bf16_t* g, bf16_t* l){
    __builtin_amdgcn_global_load_lds(
        (const __attribute__((address_space(1))) void*)g,
        (__attribute__((address_space(3))) void*)l, 16, 0, 0);
}

// group barrier: monotonic counter, agent scope (proven in r3).
__device__ __forceinline__ void group_barrier(int* bar, int target){
    __syncthreads();
    if (threadIdx.x == 0){
        __threadfence();
        __hip_atomic_fetch_add(bar, 1, __ATOMIC_RELAXED, __HIP_MEMORY_SCOPE_AGENT);
        while (__hip_atomic_load(bar, __ATOMIC_RELAXED, __HIP_MEMORY_SCOPE_AGENT) < target)
            __builtin_amdgcn_s_sleep(2);
        __threadfence();
    }
    __syncthreads();
}

// ---------------------------------------------------------------------------
// Multi-segment fp32 -> bf16 cast (up to 4 segments per launch)
// ---------------------------------------------------------------------------
struct CastSeg { const float* s; bf16_t* d; int n4; };

__global__ void mcast_kernel(CastSeg s0, CastSeg s1, CastSeg s2, CastSeg s3, int total4){
    int i = blockIdx.x*256 + threadIdx.x;
    if (i >= total4) return;
    CastSeg seg = s0;
    if (i >= seg.n4){ i -= seg.n4; seg = s1;
      if (i >= seg.n4){ i -= seg.n4; seg = s2;
        if (i >= seg.n4){ i -= seg.n4; seg = s3; } } }
    float4 f = reinterpret_cast<const float4*>(seg.s)[i];
    bf16_t o[4] = {(bf16_t)f.x,(bf16_t)f.y,(bf16_t)f.z,(bf16_t)f.w};
    reinterpret_cast<ushort4*>(seg.d)[i] = *reinterpret_cast<ushort4*>(o);
}

// ---------------------------------------------------------------------------
// Generic BT-GEMM: C[M,N] = A[M,K] @ B[N,K]^T (+bias[N]) (+add[M,N])
// ---------------------------------------------------------------------------
template<typename CT, bool RELU>
__launch_bounds__(256, 4)
__global__ void gemm_bt_kernel(const float* __restrict__ A, const bf16_t* __restrict__ B,
                               const float* __restrict__ bias, const float* __restrict__ add,
                               CT* __restrict__ C, int N, int K)
{
    __shared__ bf16_t As[64][40];
    __shared__ bf16_t Bs[64][40];
    const int tid = threadIdx.x;
    const int m0 = blockIdx.x*64, n0 = blockIdx.y*64;
    const int w = tid>>6, lane = tid&63;
    const int wm = w&1, wn = w>>1;
    const int arow = tid>>2, ac8 = (tid&3)*8;
    f32x4 acc[2][2];
    #pragma unroll
    for (int i=0;i<2;i++)
        #pragma unroll
        for (int j=0;j<2;j++) acc[i][j] = f32x4{0.f,0.f,0.f,0.f};

    for (int kk=0; kk<K; kk+=32){
        {
            const float4 f0 = *reinterpret_cast<const float4*>(&A[(size_t)(m0+arow)*K + kk + ac8]);
            const float4 f1 = *reinterpret_cast<const float4*>(&A[(size_t)(m0+arow)*K + kk + ac8 + 4]);
            bf16x8 v;
            v[0]=(bf16_t)f0.x; v[1]=(bf16_t)f0.y; v[2]=(bf16_t)f0.z; v[3]=(bf16_t)f0.w;
            v[4]=(bf16_t)f1.x; v[5]=(bf16_t)f1.y; v[6]=(bf16_t)f1.z; v[7]=(bf16_t)f1.w;
            *reinterpret_cast<bf16x8*>(&As[arow][ac8]) = v;
        }
        *reinterpret_cast<uint4*>(&Bs[arow][ac8]) =
            *reinterpret_cast<const uint4*>(&B[(size_t)(n0+arow)*K + kk + ac8]);
        __syncthreads();
        const int fr = lane&15, fk = (lane>>4)*8;
        bf16x8 a0 = *reinterpret_cast<const bf16x8*>(&As[wm*32+fr][fk]);
        bf16x8 a1 = *reinterpret_cast<const bf16x8*>(&As[wm*32+16+fr][fk]);
        bf16x8 b0 = *reinterpret_cast<const bf16x8*>(&Bs[wn*32+fr][fk]);
        bf16x8 b1 = *reinterpret_cast<const bf16x8*>(&Bs[wn*32+16+fr][fk]);
        acc[0][0] = __builtin_amdgcn_mfma_f32_16x16x32_bf16(a0,b0,acc[0][0],0,0,0);
        acc[0][1] = __builtin_amdgcn_mfma_f32_16x16x32_bf16(a0,b1,acc[0][1],0,0,0);
        acc[1][0] = __builtin_amdgcn_mfma_f32_16x16x32_bf16(a1,b0,acc[1][0],0,0,0);
        acc[1][1] = __builtin_amdgcn_mfma_f32_16x16x32_bf16(a1,b1,acc[1][1],0,0,0);
        __syncthreads();
    }
    const int fj = lane&15, fi4 = (lane>>4)*4;
    #pragma unroll
    for (int mt=0;mt<2;mt++)
        #pragma unroll
        for (int nt=0;nt<2;nt++){
            int gr = m0 + wm*32 + mt*16 + fi4;
            int gc = n0 + wn*32 + nt*16 + fj;
            float bv = bias ? bias[gc] : 0.f;
            #pragma unroll
            for (int r=0;r<4;r++){
                float v = acc[mt][nt][r] + bv;
                if (add) v += add[(size_t)(gr+r)*N + gc];
                if (RELU) v = fmaxf(v, 0.f);
                C[(size_t)(gr+r)*N + gc] = (CT)v;
            }
        }
}

// ---------------------------------------------------------------------------
// Stage-1 persistent token-GRU: batch 1536, hidden 768, 24 steps.
// grid (24,24) = 576 blocks; block = 64 rows x 32 h-cols (96 gate rows).
// __launch_bounds__(256,4): VGPR cap 128 -> >=4 blocks/CU residency (1024>=576),
// guaranteeing the group barrier cannot deadlock.
// B tiles via swizzled DMA: k-quarter q ^= (row>>1)&3 on BOTH stage (global
// src) and read -> 2-way LDS conflict only (free, m136).
// ---------------------------------------------------------------------------
__launch_bounds__(256, 4)
__global__ void gru_seq_kernel(float* __restrict__ h_a, float* __restrict__ h_b,
                               const bf16_t* __restrict__ Whh,   // [2304,768]
                               const float* __restrict__ E,      // [64,2304]
                               const float* __restrict__ bhh,
                               const int* __restrict__ paths,
                               const int* __restrict__ src_idx,
                               int* __restrict__ bars)
{
    __shared__ bf16_t As[2][64][40];
    __shared__ bf16_t Bs[2][96][32];
    __shared__ int tok_s[64];

    const int tid = threadIdx.x;
    const int s0 = blockIdx.x*64, c0 = blockIdx.y*32;
    const int lane = tid&63, w = tid>>6;
    const int wm = w&1, wn = w>>1;
    const int arow = tid>>2, ac8 = (tid&3)*8;
    const int fr = lane&15, fkq = lane>>4, fk = fkq*8;
    const int ec = c0 + wn*16 + fr;
    const int er0 = s0 + wm*32 + fkq*4;
    int* bar = bars + blockIdx.x;

    const float bh_r = bhh[ec], bh_z = bhh[Dv+ec], bh_n = bhh[2*Dv+ec];

    for (int t=0; t<Pv; ++t){
        const float* h_old = (t&1) ? h_b : h_a;
        float*       h_new = (t&1) ? h_a : h_b;
        if (tid < 64){
            int s = s0 + tid;
            int b = s / KLv;
            tok_s[tid] = paths[(src_idx[b]*KLv + (s - b*KLv))*Pv + t];
        }
        f32x4 acc[2][3];
        #pragma unroll
        for (int i=0;i<2;i++)
            #pragma unroll
            for (int j=0;j<3;j++) acc[i][j] = f32x4{0.f,0.f,0.f,0.f};

        // prologue: kk=0 into buf 0
        {
            const float4 f0 = *(const float4*)&h_old[(size_t)(s0+arow)*Dv + ac8];
            const float4 f1 = *(const float4*)&h_old[(size_t)(s0+arow)*Dv + ac8 + 4];
            #pragma unroll
            for (int i=0;i<2;i++){
                int idx = tid + 256*i;
                if (idx < 384){
                    int row = idx>>2, q = idx&3;
                    int qs = q ^ ((row>>1)&3);
                    int grow = (row>>5)*Dv + c0 + (row&31);
                    gld_lds16(&Whh[(size_t)grow*Dv + qs*8], &Bs[0][0][0] + idx*8);
                }
            }
            bf16x8 v;
            v[0]=(bf16_t)f0.x; v[1]=(bf16_t)f0.y; v[2]=(bf16_t)f0.z; v[3]=(bf16_t)f0.w;
            v[4]=(bf16_t)f1.x; v[5]=(bf16_t)f1.y; v[6]=(bf16_t)f1.z; v[7]=(bf16_t)f1.w;
            *(bf16x8*)&As[0][arow][ac8] = v;
        }
        int cur = 0;
        for (int ki=0; ki<24; ++ki){
            __syncthreads();     // drains DMA vmcnt: buf[cur] complete
            float4 f0, f1;
            if (ki < 23){
                int kk = (ki+1)*32;
                f0 = *(const float4*)&h_old[(size_t)(s0+arow)*Dv + kk + ac8];
                f1 = *(const float4*)&h_old[(size_t)(s0+arow)*Dv + kk + ac8 + 4];
                #pragma unroll
                for (int i=0;i<2;i++){
                    int idx = tid + 256*i;
                    if (idx < 384){
                        int row = idx>>2, q = idx&3;
                        int qs = q ^ ((row>>1)&3);
                        int grow = (row>>5)*Dv + c0 + (row&31);
                        gld_lds16(&Whh[(size_t)grow*Dv + kk + qs*8], &Bs[cur^1][0][0] + idx*8);
                    }
                }
            }
            const bf16_t* ab = &As[cur][0][0];
            const bf16_t* bb = &Bs[cur][0][0];
            bf16x8 a0 = *(const bf16x8*)(ab + (wm*32+fr)*40 + fk);
            bf16x8 a1 = *(const bf16x8*)(ab + (wm*32+16+fr)*40 + fk);
            #pragma unroll
            for (int g=0; g<3; ++g){
                int brow = g*32 + wn*16 + fr;
                bf16x8 bfr = *(const bf16x8*)(bb + brow*32 + ((fkq ^ ((brow>>1)&3))*8));
                acc[0][g] = __builtin_amdgcn_mfma_f32_16x16x32_bf16(a0, bfr, acc[0][g],0,0,0);
                acc[1][g] = __builtin_amdgcn_mfma_f32_16x16x32_bf16(a1, bfr, acc[1][g],0,0,0);
            }
            if (ki < 23){
                bf16x8 v;
                v[0]=(bf16_t)f0.x; v[1]=(bf16_t)f0.y; v[2]=(bf16_t)f0.z; v[3]=(bf16_t)f0.w;
                v[4]=(bf16_t)f1.x; v[5]=(bf16_t)f1.y; v[6]=(bf16_t)f1.z; v[7]=(bf16_t)f1.w;
                *(bf16x8*)&As[cur^1][arow][ac8] = v;
            }
            cur ^= 1;
        }
        // epilogue: gates in registers
        #pragma unroll
        for (int mt=0; mt<2; ++mt)
            #pragma unroll
            for (int r4=0; r4<4; ++r4){
                int s = er0 + mt*16 + r4;
                const float* Erow = E + (size_t)tok_s[s - s0]*G1v;
                float gr  = Erow[ec]      + acc[mt][0][r4] + bh_r;
                float gz  = Erow[Dv+ec]   + acc[mt][1][r4] + bh_z;
                float gnx = Erow[2*Dv+ec];
                float ghn = acc[mt][2][r4] + bh_n;
                float r = sigmf(gr), z = sigmf(gz);
                float n = tanhft(gnx + r*ghn);
                float hp = h_old[(size_t)s*Dv + ec];
                h_new[(size_t)s*Dv + ec] = (1.f - z)*n + z*hp;
            }
        if (t < Pv-1) group_barrier(bar, 24*(t+1));
    }
}

// ---------------------------------------------------------------------------
// Stage-2 persistent bidirectional GRU: batch 192, hidden 384, 8 steps.
// grid (6,24,2) = 288 blocks; block = 32 rows x 16 h-cols, 128 threads.
// __launch_bounds__(128,4): VGPR cap 128 -> 8 blocks/CU residency (2048>=288).
// ---------------------------------------------------------------------------
__launch_bounds__(128, 4)
__global__ void gru1_seq_kernel(float* __restrict__ hf_a, float* __restrict__ hf_b,
                                float* __restrict__ hb_a, float* __restrict__ hb_b,
                                const bf16_t* __restrict__ Whf, const bf16_t* __restrict__ Whb,
                                const bf16_t* __restrict__ xg1,
                                const float* __restrict__ bhf, const float* __restrict__ bhb,
                                float* __restrict__ sub, int* __restrict__ bars)
{
    __shared__ bf16_t As[2][32][40];
    __shared__ bf16_t Bs[2][48][32];
    const int tid = threadIdx.x;
    const int dir = blockIdx.z;
    float* bufA = dir ? hb_a : hf_a;
    float* bufB = dir ? hb_b : hf_b;
    const bf16_t* Whh = dir ? Whb : Whf;
    const bf16_t* xg  = xg1 + dir*G2v;
    const float* bhh  = dir ? bhb : bhf;
    int* bar = bars + dir*6 + blockIdx.x;

    const int s0 = blockIdx.x*32, c0 = blockIdx.y*16;
    const int lane = tid&63, wm = tid>>6;
    const int arow = tid>>2, ac8 = (tid&3)*8;
    const int fr = lane&15, fkq = lane>>4, fk = fkq*8;
    const int ec = c0 + fr;
    const int er0 = s0 + wm*16 + fkq*4;
    const float bh_r = bhh[ec], bh_z = bhh[H1v+ec], bh_n = bhh[2*H1v+ec];
    float ym[4];

    for (int t=0; t<Lv; ++t){
        const float* h_old = (t&1) ? bufB : bufA;
        float*       h_new = (t&1) ? bufA : bufB;
        const int lidx = dir ? (Lv-1-t) : t;
        f32x4 acc[3];
        acc[0]=acc[1]=acc[2]=f32x4{0.f,0.f,0.f,0.f};
        {
            const float4 f0 = *(const float4*)&h_old[(size_t)(s0+arow)*H1v + ac8];
            const float4 f1 = *(const float4*)&h_old[(size_t)(s0+arow)*H1v + ac8 + 4];
            #pragma unroll
            for (int i=0;i<2;i++){
                int idx = tid + 128*i;
                if (idx < 192){
                    int row = idx>>2, q = idx&3;
                    int qs = q ^ ((row>>1)&3);
                    int grow = (row>>4)*H1v + c0 + (row&15);
                    gld_lds16(&Whh[(size_t)grow*H1v + qs*8], &Bs[0][0][0] + idx*8);
                }
            }
            bf16x8 v;
            v[0]=(bf16_t)f0.x; v[1]=(bf16_t)f0.y; v[2]=(bf16_t)f0.z; v[3]=(bf16_t)f0.w;
            v[4]=(bf16_t)f1.x; v[5]=(bf16_t)f1.y; v[6]=(bf16_t)f1.z; v[7]=(bf16_t)f1.w;
            *(bf16x8*)&As[0][arow][ac8] = v;
        }
        int cur = 0;
        for (int ki=0; ki<12; ++ki){
            __syncthreads();
            float4 f0, f1;
            if (ki < 11){
                int kk = (ki+1)*32;
                f0 = *(const float4*)&h_old[(size_t)(s0+arow)*H1v + kk + ac8];
                f1 = *(const float4*)&h_old[(size_t)(s0+arow)*H1v + kk + ac8 + 4];
                #pragma unroll
                for (int i=0;i<2;i++){
                    int idx = tid + 128*i;
                    if (idx < 192){
                        int row = idx>>2, q = idx&3;
                        int qs = q ^ ((row>>1)&3);
                        int grow = (row>>4)*H1v + c0 + (row&15);
                        gld_lds16(&Whh[(size_t)grow*H1v + kk + qs*8], &Bs[cur^1][0][0] + idx*8);
                    }
                }
            }
            const bf16_t* ab = &As[cur][0][0];
            const bf16_t* bb = &Bs[cur][0][0];
            bf16x8 afr = *(const bf16x8*)(ab + (wm*16+fr)*40 + fk);
            #pragma unroll
            for (int g=0; g<3; ++g){
                int brow = g*16 + fr;
                bf16x8 bfr = *(const bf16x8*)(bb + brow*32 + ((fkq ^ ((brow>>1)&3))*8));
                acc[g] = __builtin_amdgcn_mfma_f32_16x16x32_bf16(afr, bfr, acc[g],0,0,0);
            }
            if (ki < 11){
                bf16x8 v;
                v[0]=(bf16_t)f0.x; v[1]=(bf16_t)f0.y; v[2]=(bf16_t)f0.z; v[3]=(bf16_t)f0.w;
                v[4]=(bf16_t)f1.x; v[5]=(bf16_t)f1.y; v[6]=(bf16_t)f1.z; v[7]=(bf16_t)f1.w;
                *(bf16x8*)&As[cur^1][arow][ac8] = v;
            }
            cur ^= 1;
        }
        #pragma unroll
        for (int r4=0;r4<4;r4++){
            int s = er0 + r4;
            const bf16_t* xrow = xg + ((size_t)(s*Lv + lidx))*(2*G2v);
            float gr  = (float)xrow[ec]       + acc[0][r4] + bh_r;
            float gz  = (float)xrow[H1v+ec]   + acc[1][r4] + bh_z;
            float gnx = (float)xrow[2*H1v+ec];
            float ghn = acc[2][r4] + bh_n;
            float r = sigmf(gr), z = sigmf(gz);
            float n = tanhft(gnx + r*ghn);
            float hp = h_old[(size_t)s*H1v + ec];
            float hv = (1.f - z)*n + z*hp;
            h_new[(size_t)s*H1v + ec] = hv;
            ym[r4] = (t==0) ? hv : fmaxf(ym[r4], hv);
        }
        if (t < Lv-1) group_barrier(bar, 24*(t+1));
    }
    #pragma unroll
    for (int r4=0;r4<4;r4++){
        int s = er0 + r4;
        sub[(size_t)s*Dv + dir*H1v + ec] = fmaxf(ym[r4], 0.f);
    }
}

// ---------------------------------------------------------------------------
// Stage-3 persistent bidirectional LSTM: batch 16, hidden 384, 12 steps.
// grid (24,2) = 48 blocks; block = 16 h-cols (64 gate rows), 64 threads.
// ---------------------------------------------------------------------------
__launch_bounds__(64, 4)
__global__ void lstm_seq_kernel(float* __restrict__ hf_a, float* __restrict__ hf_b,
                                float* __restrict__ hb_a, float* __restrict__ hb_b,
                                const bf16_t* __restrict__ Wf, const bf16_t* __restrict__ Wb, // [1536,384]
                                const bf16_t* __restrict__ xg2,
                                const float* __restrict__ bhf, const float* __restrict__ bhb,
                                float* __restrict__ tempmax, int* __restrict__ bars)
{
    __shared__ bf16_t As[2][16][40];
    __shared__ bf16_t Bs[2][64][32];
    const int tid = threadIdx.x;
    const int dir = blockIdx.y;
    float* bufA = dir ? hb_a : hf_a;
    float* bufB = dir ? hb_b : hf_b;
    const bf16_t* Whh = dir ? Wb : Wf;
    const bf16_t* xg  = xg2 + dir*G3v;
    const float* bhh  = dir ? bhb : bhf;
    int* bar = bars + dir;
    const int c0 = blockIdx.x*16;
    const int lane = tid&63;
    const int arow = tid>>2, ac8 = (tid&3)*8;
    const int fr = lane&15, fkq = lane>>4, fk = fkq*8;
    const int hcol = c0 + fr;
    const int r0 = fkq*4;
    float bh[4];
    #pragma unroll
    for (int g=0; g<4; ++g) bh[g] = bhh[g*H1v + hcol];
    float cst[4] = {0.f,0.f,0.f,0.f};
    float tm[4];

    for (int t=0; t<Kv; ++t){
        const float* h_old = (t&1) ? bufB : bufA;
        float*       h_new = (t&1) ? bufA : bufB;
        const int lidx = dir ? (Kv-1-t) : t;
        f32x4 acc[4];
        acc[0]=acc[1]=acc[2]=acc[3]=f32x4{0.f,0.f,0.f,0.f};
        {
            const float4 f0 = *(const float4*)&h_old[(size_t)arow*H1v + ac8];
            const float4 f1 = *(const float4*)&h_old[(size_t)arow*H1v + ac8 + 4];
            #pragma unroll
            for (int i=0;i<4;i++){
                int idx = tid + 64*i;
                int row = idx>>2, q = idx&3;
                int qs = q ^ ((row>>1)&3);
                int grow = (row>>4)*H1v + c0 + (row&15);
                gld_lds16(&Whh[(size_t)grow*H1v + qs*8], &Bs[0][0][0] + idx*8);
            }
            bf16x8 v;
            v[0]=(bf16_t)f0.x; v[1]=(bf16_t)f0.y; v[2]=(bf16_t)f0.z; v[3]=(bf16_t)f0.w;
            v[4]=(bf16_t)f1.x; v[5]=(bf16_t)f1.y; v[6]=(bf16_t)f1.z; v[7]=(bf16_t)f1.w;
            *(bf16x8*)&As[0][arow][ac8] = v;
        }
        int cur = 0;
        for (int ki=0; ki<12; ++ki){
            __syncthreads();
            float4 f0, f1;
            if (ki < 11){
                int kk = (ki+1)*32;
                f0 = *(const float4*)&h_old[(size_t)arow*H1v + kk + ac8];
                f1 = *(const float4*)&h_old[(size_t)arow*H1v + kk + ac8 + 4];
                #pragma unroll
                for (int i=0;i<4;i++){
                    int idx = tid + 64*i;
                    int row = idx>>2, q = idx&3;
                    int qs = q ^ ((row>>1)&3);
                    int grow = (row>>4)*H1v + c0 + (row&15);
                    gld_lds16(&Whh[(size_t)grow*H1v + kk + qs*8], &Bs[cur^1][0][0] + idx*8);
                }
            }
            const bf16_t* ab = &As[cur][0][0];
            const bf16_t* bb = &Bs[cur][0][0];
            bf16x8 afr = *(const bf16x8*)(ab + fr*40 + fk);
            #pragma unroll
            for (int g=0; g<4; ++g){
                int brow = g*16 + fr;
                bf16x8 bfr = *(const bf16x8*)(bb + brow*32 + ((fkq ^ ((brow>>1)&3))*8));
                acc[g] = __builtin_amdgcn_mfma_f32_16x16x32_bf16(afr, bfr, acc[g],0,0,0);
            }
            if (ki < 11){
                bf16x8 v;
                v[0]=(bf16_t)f0.x; v[1]=(bf16_t)f0.y; v[2]=(bf16_t)f0.z; v[3]=(bf16_t)f0.w;
                v[4]=(bf16_t)f1.x; v[5]=(bf16_t)f1.y; v[6]=(bf16_t)f1.z; v[7]=(bf16_t)f1.w;
                *(bf16x8*)&As[cur^1][arow][ac8] = v;
            }
            cur ^= 1;
        }
        #pragma unroll
        for (int r4=0;r4<4;r4++){
            int r = r0 + r4;
            const bf16_t* xrow = xg + ((size_t)(r*Kv + lidx))*(2*G3v);
            float ai = (float)xrow[hcol]        + acc[0][r4] + bh[0];
            float af = (float)xrow[H1v+hcol]    + acc[1][r4] + bh[1];
            float ag = (float)xrow[2*H1v+hcol]  + acc[2][r4] + bh[2];
            float ao = (float)xrow[3*H1v+hcol]  + acc[3][r4] + bh[3];
            float iv = sigmf(ai), fv = sigmf(af), gv = tanhft(ag), ov = sigmf(ao);
            cst[r4] = fv*cst[r4] + iv*gv;
            float hn = ov*tanhft(cst[r4]);
            h_new[(size_t)r*H1v + hcol] = hn;
            tm[r4] = (t==0) ? hn : fmaxf(tm[r4], hn);
        }
        if (t < Kv-1) group_barrier(bar, 24*(t+1));
    }
    #pragma unroll
    for (int r4=0;r4<4;r4++)
        tempmax[(size_t)(r0+r4)*Dv + dir*H1v + hcol] = tm[r4];
}

// ---------------------------------------------------------------------------
// Head kernels (fp32, batch = 16)
// ---------------------------------------------------------------------------
__global__ void bn_kernel(const float* __restrict__ x, const float* __restrict__ g,
                          const float* __restrict__ b, float* __restrict__ y, int Dcols){
    int c = blockIdx.x*256 + threadIdx.x;
    if (c >= Dcols) return;
    float mu = 0.f;
    for (int r=0;r<Bv;r++) mu += x[r*Dcols + c];
    mu *= (1.f/Bv);
    float var = 0.f;
    for (int r=0;r<Bv;r++){ float d = x[r*Dcols + c] - mu; var += d*d; }
    var *= (1.f/Bv);
    float sc = g[c]*rsqrtf(var + 1e-5f);
    for (int r=0;r<Bv;r++) y[r*Dcols + c] = sc*(x[r*Dcols + c] - mu) + b[c];
}

__global__ void out_kernel(const float* __restrict__ A, const float* __restrict__ W,
                           const float* __restrict__ b, float* __restrict__ out){
    int bb = blockIdx.x, lane = threadIdx.x;  // 64 threads
    float s = 0.f;
    for (int k=lane;k<Dv;k+=64) s += A[bb*Dv + k]*W[k];
    #pragma unroll
    for (int off=32;off;off>>=1) s += __shfl_down(s,off);
    if (lane==0) out[bb] = 1.f/(1.f + __expf(-(s + b[0])));
}

// ---------------------------------------------------------------------------
// Launch
// ---------------------------------------------------------------------------
extern "C" void kernel_launch(void* const* d_in, const int* in_sizes, int n_in,
                              void* d_out, int out_size, void* d_ws, size_t ws_size,
                              hipStream_t stream) {
    const float* feature = (const float*)d_in[0];
    const int*   src_idx = (const int*)d_in[1];
    const int*   paths   = (const int*)d_in[2];
    const float* emb     = (const float*)d_in[3];
    const float* gWih    = (const float*)d_in[4];
    const float* gWhh    = (const float*)d_in[5];
    const float* gbih    = (const float*)d_in[6];
    const float* gbhh    = (const float*)d_in[7];
    const float* g1fWih  = (const float*)d_in[8];
    const float* g1fWhh  = (const float*)d_in[9];
    const float* g1fbih  = (const float*)d_in[10];
    const float* g1fbhh  = (const float*)d_in[11];
    const float* g1bWih  = (const float*)d_in[12];
    const float* g1bWhh  = (const float*)d_in[13];
    const float* g1bbih  = (const float*)d_in[14];
    const float* g1bbhh  = (const float*)d_in[15];
    const float* lfWih   = (const float*)d_in[16];
    const float* lfWhh   = (const float*)d_in[17];
    const float* lfbih   = (const float*)d_in[18];
    const float* lfbhh   = (const float*)d_in[19];
    const float* lbWih   = (const float*)d_in[20];
    const float* lbWhh   = (const float*)d_in[21];
    const float* lbbih   = (const float*)d_in[22];
    const float* lbbhh   = (const float*)d_in[23];
    const float* treeW   = (const float*)d_in[24];
    const float* treeb   = (const float*)d_in[25];
    const float* bn1g    = (const float*)d_in[26];
    const float* bn1b    = (const float*)d_in[27];
    const float* bn2g    = (const float*)d_in[28];
    const float* bn2b    = (const float*)d_in[29];
    const float* d1W     = (const float*)d_in[30];
    const float* d1b     = (const float*)d_in[31];
    const float* d2W     = (const float*)d_in[32];
    const float* d2b     = (const float*)d_in[33];
    const float* outW    = (const float*)d_in[34];
    const float* outb    = (const float*)d_in[35];
    float* out = (float*)d_out;

    // ---- workspace (~26.4 MB, matching the r2/r3 passing footprint) ----
    char* ws = (char*)d_ws;
    size_t off = 0;
    auto alloc = [&](size_t bytes)->char*{
        char* p = ws + off;
        off += (bytes + 255) & ~(size_t)255;
        return p;
    };
    float*  E      = (float*)alloc((size_t)64*G1v*4);
    char*   Wreg   = alloc(4718592);                          // time-shared weight scratch
    float*  emb_pad= (float*)alloc((size_t)64*Dv*4);
    float*  h_a    = (float*)alloc((size_t)N1v*Dv*4);         // phase4: lWf/lWb casts
    float*  h_b    = (float*)alloc((size_t)N1v*Dv*4);         // later: leafs
    bf16_t* xg1    = (bf16_t*)alloc((size_t)N1v*2*G2v*2);     // [1536][2304]
    bf16_t* xg2    = (bf16_t*)alloc((size_t)BKv*2*G3v*2);     // [192][3072]
    float*  h1f_a  = (float*)alloc((size_t)BKv*H1v*4);
    float*  h1f_b  = (float*)alloc((size_t)BKv*H1v*4);
    float*  h1b_a  = (float*)alloc((size_t)BKv*H1v*4);
    float*  h1b_b  = (float*)alloc((size_t)BKv*H1v*4);
    float*  sub    = (float*)alloc((size_t)BKv*Dv*4);
    float*  lhf_a  = (float*)alloc((size_t)Bv*H1v*4);
    float*  lhf_b  = (float*)alloc((size_t)Bv*H1v*4);
    float*  lhb_a  = (float*)alloc((size_t)Bv*H1v*4);
    float*  lhb_b  = (float*)alloc((size_t)Bv*H1v*4);
    float*  tempmax= (float*)alloc((size_t)Bv*Dv*4);
    float*  hb1    = (float*)alloc((size_t)64*Dv*4);
    float*  hd1    = (float*)alloc((size_t)64*G3v*4);
    float*  hb2    = (float*)alloc((size_t)64*G3v*4);
    float*  hd2    = (float*)alloc((size_t)64*Dv*4);
    float*  bias1  = (float*)alloc((size_t)2*G2v*4);
    float*  bias2  = (float*)alloc((size_t)2*G3v*4);
    int*    bars   = (int*)alloc(256);
    int* bars1 = bars;        // 24 groups (stage 1)
    int* bars2 = bars + 24;   // 12 groups (stage 2)
    int* bars3 = bars + 36;   // 2 groups  (lstm)
    (void)ws_size; (void)in_sizes; (void)n_in; (void)out_size;

    // time-shared aliases inside Wreg (stream order serializes phases)
    bf16_t* gWih_bf  = (bf16_t*)Wreg;                         // phase 1a (3,538,944)
    bf16_t* Whh_bf   = (bf16_t*)Wreg;                         // phase 1b (after E-GEMM)
    bf16_t* treeW_bf = (bf16_t*)Wreg;                         // phase 2
    bf16_t* w1fb_bf  = (bf16_t*)(Wreg + 1179648);             // [2304][768]
    bf16_t* u1f_bf   = (bf16_t*)Wreg;                         // phase 3
    bf16_t* u1b_bf   = (bf16_t*)(Wreg + 884736);
    bf16_t* lwfb_bf  = (bf16_t*)Wreg;                         // phase 4: [3072][768]
    bf16_t* lWf_bf   = (bf16_t*)h_a;                          // phase 4: h_a is dead
    bf16_t* lWb_bf   = (bf16_t*)((char*)h_a + 1179648);
    bf16_t* d1W_bf   = (bf16_t*)Wreg;                         // phase 5
    bf16_t* d2W_bf   = (bf16_t*)(Wreg + 2359296);

    auto mcast = [&](CastSeg a, CastSeg b, CastSeg c, CastSeg d){
        int total4 = a.n4 + b.n4 + c.n4 + d.n4;
        mcast_kernel<<<(total4+255)/256, 256, 0, stream>>>(a, b, c, d, total4);
    };
    CastSeg nil{nullptr,nullptr,0};

    // ---- init (ws is re-poisoned before every call) ----
    hipMemsetAsync(bars, 0, 256, stream);
    hipMemsetAsync(emb_pad, 0, (size_t)64*Dv*4, stream);
    hipMemsetAsync(h_a,   0, (size_t)N1v*Dv*4, stream);
    hipMemsetAsync(h1f_a, 0, (size_t)BKv*H1v*4, stream);
    hipMemsetAsync(h1b_a, 0, (size_t)BKv*H1v*4, stream);
    hipMemsetAsync(lhf_a, 0, (size_t)Bv*H1v*4, stream);
    hipMemsetAsync(lhb_a, 0, (size_t)Bv*H1v*4, stream);
    hipMemsetAsync(hb1,   0, (size_t)64*Dv*4, stream);
    hipMemsetAsync(hb2,   0, (size_t)64*G3v*4, stream);
    hipMemcpyAsync(emb_pad, emb, (size_t)Vv*Dv*4, hipMemcpyDeviceToDevice, stream);
    hipMemcpyAsync(bias1,       g1fbih, G2v*4, hipMemcpyDeviceToDevice, stream);
    hipMemcpyAsync(bias1+G2v,   g1bbih, G2v*4, hipMemcpyDeviceToDevice, stream);
    hipMemcpyAsync(bias2,       lfbih,  G3v*4, hipMemcpyDeviceToDevice, stream);
    hipMemcpyAsync(bias2+G3v,   lbbih,  G3v*4, hipMemcpyDeviceToDevice, stream);

    // ---- phase 1: E = emb @ gWih^T + gbih, then stage-1 persistent GRU ----
    mcast({gWih, gWih_bf, G1v*Dv/4}, nil, nil, nil);
    gemm_bt_kernel<float,false><<<dim3(1, G1v/64), 256, 0, stream>>>(emb_pad, gWih_bf, gbih, nullptr, E, G1v, Dv);
    mcast({gWhh, Whh_bf, G1v*Dv/4}, nil, nil, nil);   // aliases gWih_bf; after E-GEMM
    gru_seq_kernel<<<dim3(N1v/64, Dv/32), 256, 0, stream>>>(h_a, h_b, Whh_bf, E, gbhh, paths, src_idx, bars1);

    // ---- phase 2: leafs + stage-2 input projection (merged dirs) ----
    mcast({treeW, treeW_bf, Dv*Dv/4}, {g1fWih, w1fb_bf, G2v*Dv/4},
          {g1bWih, w1fb_bf + (size_t)G2v*Dv, G2v*Dv/4}, nil);
    float* leafs = h_b;
    gemm_bt_kernel<float,false><<<dim3(N1v/64, Dv/64), 256, 0, stream>>>(feature, treeW_bf, treeb, h_a, leafs, Dv, Dv);
    gemm_bt_kernel<bf16_t,false><<<dim3(N1v/64, 2*G2v/64), 256, 0, stream>>>(leafs, w1fb_bf, bias1, nullptr, xg1, 2*G2v, Dv);

    // ---- phase 3: stage-2 persistent bidirectional GRU ----
    mcast({g1fWhh, u1f_bf, G2v*H1v/4}, {g1bWhh, u1b_bf, G2v*H1v/4}, nil, nil);
    gru1_seq_kernel<<<dim3(BKv/32, H1v/16, 2), 128, 0, stream>>>(
        h1f_a, h1f_b, h1b_a, h1b_b, u1f_bf, u1b_bf, xg1, g1fbhh, g1bbhh, sub, bars2);

    // ---- phase 4: stage-3 input projection + persistent LSTM ----
    // (lWf/lWb casts land in dead h_a region)
    mcast({lfWih, lwfb_bf, G3v*Dv/4}, {lbWih, lwfb_bf + (size_t)G3v*Dv, G3v*Dv/4},
          {lfWhh, lWf_bf, G3v*H1v/4}, {lbWhh, lWb_bf, G3v*H1v/4});
    gemm_bt_kernel<bf16_t,false><<<dim3(BKv/64, 2*G3v/64), 256, 0, stream>>>(sub, lwfb_bf, bias2, nullptr, xg2, 2*G3v, Dv);
    lstm_seq_kernel<<<dim3(H1v/16, 2), 64, 0, stream>>>(
        lhf_a, lhf_b, lhb_a, lhb_b, lWf_bf, lWb_bf, xg2, lfbhh, lbbhh, tempmax, bars3);

    // ---- phase 5: head (M padded to 64; pad rows zeroed each call) ----
    mcast({d1W, d1W_bf, G3v*Dv/4}, {d2W, d2W_bf, Dv*G3v/4}, nil, nil);
    bn_kernel<<<(Dv+255)/256, 256, 0, stream>>>(tempmax, bn1g, bn1b, hb1, Dv);
    gemm_bt_kernel<float,true><<<dim3(1, G3v/64), 256, 0, stream>>>(hb1, d1W_bf, d1b, nullptr, hd1, G3v, Dv);
    bn_kernel<<<(G3v+255)/256, 256, 0, stream>>>(hd1, bn2g, bn2b, hb2, G3v);
    gemm_bt_kernel<float,true><<<dim3(1, Dv/64), 256, 0, stream>>>(hb2, d2W_bf, d2b, nullptr, hd2, Dv, G3v);
    out_kernel<<<Bv, 64, 0, stream>>>(hd2, outW, outb, out);
}

// Round 6
// 1245.466 us; speedup vs baseline: 2.0390x; 2.0390x over previous
//
#include <hip/hip_runtime.h>

// ---------------------------------------------------------------------------
// Dims (fixed by the reference)
// ---------------------------------------------------------------------------
#define Bv 16
#define Kv 12
#define Lv 8
#define Pv 24
#define Dv 768
#define H1v 384
#define Vv 44
#define KLv 96          // K*L
#define N1v 1536        // B*K*L
#define BKv 192         // B*K
#define G1v 2304        // 3*D
#define G2v 1152        // 3*H1
#define G3v 1536        // 4*H1

typedef __bf16 bf16_t;
typedef __attribute__((ext_vector_type(8))) __bf16 bf16x8;
typedef __attribute__((ext_vector_type(4))) float f32x4;

__device__ __forceinline__ float sigmf(float x){ return 1.0f/(1.0f + __expf(-x)); }
__device__ __forceinline__ float tanhft(float x){ float e = __expf(2.f*x); return 1.f - 2.f/(e+1.f); }

// group barrier: monotonic counter, agent scope (proven r3/r5). bar points at
// a counter in its own 64B cacheline.
__device__ __forceinline__ void group_barrier(int* bar, int target){
    __syncthreads();
    if (threadIdx.x == 0){
        __threadfence();
        __hip_atomic_fetch_add(bar, 1, __ATOMIC_RELAXED, __HIP_MEMORY_SCOPE_AGENT);
        while (__hip_atomic_load(bar, __ATOMIC_RELAXED, __HIP_MEMORY_SCOPE_AGENT) < target)
            __builtin_amdgcn_s_sleep(2);
        __threadfence();
    }
    __syncthreads();
}

// ---------------------------------------------------------------------------
// Multi-segment fp32 -> bf16 cast (up to 4 segments per launch)
// ---------------------------------------------------------------------------
struct CastSeg { const float* s; bf16_t* d; int n4; };

__global__ void mcast_kernel(CastSeg s0, CastSeg s1, CastSeg s2, CastSeg s3, int total4){
    int i = blockIdx.x*256 + threadIdx.x;
    if (i >= total4) return;
    CastSeg seg = s0;
    if (i >= seg.n4){ i -= seg.n4; seg = s1;
      if (i >= seg.n4){ i -= seg.n4; seg = s2;
        if (i >= seg.n4){ i -= seg.n4; seg = s3; } } }
    float4 f = reinterpret_cast<const float4*>(seg.s)[i];
    bf16_t o[4] = {(bf16_t)f.x,(bf16_t)f.y,(bf16_t)f.z,(bf16_t)f.w};
    reinterpret_cast<ushort4*>(seg.d)[i] = *reinterpret_cast<ushort4*>(o);
}

// ---------------------------------------------------------------------------
// Generic BT-GEMM: C[M,N] = A[M,K] @ B[N,K]^T (+bias[N]) (+add[M,N], AT type)
// ---------------------------------------------------------------------------
template<typename CT, typename AT, bool RELU>
__launch_bounds__(256, 4)
__global__ void gemm_bt_kernel(const float* __restrict__ A, const bf16_t* __restrict__ B,
                               const float* __restrict__ bias, const AT* __restrict__ add,
                               CT* __restrict__ C, int N, int K)
{
    __shared__ bf16_t As[64][40];
    __shared__ bf16_t Bs[64][40];
    const int tid = threadIdx.x;
    const int m0 = blockIdx.x*64, n0 = blockIdx.y*64;
    const int w = tid>>6, lane = tid&63;
    const int wm = w&1, wn = w>>1;
    const int arow = tid>>2, ac8 = (tid&3)*8;
    f32x4 acc[2][2];
    #pragma unroll
    for (int i=0;i<2;i++)
        #pragma unroll
        for (int j=0;j<2;j++) acc[i][j] = f32x4{0.f,0.f,0.f,0.f};

    for (int kk=0; kk<K; kk+=32){
        {
            const float4 f0 = *reinterpret_cast<const float4*>(&A[(size_t)(m0+arow)*K + kk + ac8]);
            const float4 f1 = *reinterpret_cast<const float4*>(&A[(size_t)(m0+arow)*K + kk + ac8 + 4]);
            bf16x8 v;
            v[0]=(bf16_t)f0.x; v[1]=(bf16_t)f0.y; v[2]=(bf16_t)f0.z; v[3]=(bf16_t)f0.w;
            v[4]=(bf16_t)f1.x; v[5]=(bf16_t)f1.y; v[6]=(bf16_t)f1.z; v[7]=(bf16_t)f1.w;
            *reinterpret_cast<bf16x8*>(&As[arow][ac8]) = v;
        }
        *reinterpret_cast<uint4*>(&Bs[arow][ac8]) =
            *reinterpret_cast<const uint4*>(&B[(size_t)(n0+arow)*K + kk + ac8]);
        __syncthreads();
        const int fr = lane&15, fk = (lane>>4)*8;
        bf16x8 a0 = *reinterpret_cast<const bf16x8*>(&As[wm*32+fr][fk]);
        bf16x8 a1 = *reinterpret_cast<const bf16x8*>(&As[wm*32+16+fr][fk]);
        bf16x8 b0 = *reinterpret_cast<const bf16x8*>(&Bs[wn*32+fr][fk]);
        bf16x8 b1 = *reinterpret_cast<const bf16x8*>(&Bs[wn*32+16+fr][fk]);
        acc[0][0] = __builtin_amdgcn_mfma_f32_16x16x32_bf16(a0,b0,acc[0][0],0,0,0);
        acc[0][1] = __builtin_amdgcn_mfma_f32_16x16x32_bf16(a0,b1,acc[0][1],0,0,0);
        acc[1][0] = __builtin_amdgcn_mfma_f32_16x16x32_bf16(a1,b0,acc[1][0],0,0,0);
        acc[1][1] = __builtin_amdgcn_mfma_f32_16x16x32_bf16(a1,b1,acc[1][1],0,0,0);
        __syncthreads();
    }
    const int fj = lane&15, fi4 = (lane>>4)*4;
    #pragma unroll
    for (int mt=0;mt<2;mt++)
        #pragma unroll
        for (int nt=0;nt<2;nt++){
            int gr = m0 + wm*32 + mt*16 + fi4;
            int gc = n0 + wn*32 + nt*16 + fj;
            float bv = bias ? bias[gc] : 0.f;
            #pragma unroll
            for (int r=0;r<4;r++){
                float v = acc[mt][nt][r] + bv;
                if (add) v += (float)add[(size_t)(gr+r)*N + gc];
                if (RELU) v = fmaxf(v, 0.f);
                C[(size_t)(gr+r)*N + gc] = (CT)v;
            }
        }
}

// ---------------------------------------------------------------------------
// Stage-1 persistent token-GRU: batch 1536 (bf16 h), hidden 768, 24 steps.
// grid (8,24) = 192 blocks (<=256 -> co-residency guaranteed, 1 block/CU by
// LDS). 512 threads = 8 waves (4 row-quarters x 2 col-halves).
// Whh slice [96 gate rows][768] bf16 = 147 KB RESIDENT in LDS (loaded once,
// XOR-swizzled chunks). Inner loop: NO barriers — A-frags streamed from
// global bf16 h, B from LDS, h_prev in registers.
// ---------------------------------------------------------------------------
__launch_bounds__(512, 1)
__global__ void gru_seq_kernel(bf16_t* __restrict__ h_a, bf16_t* __restrict__ h_b,
                               const bf16_t* __restrict__ Whh,   // [2304,768]
                               const float* __restrict__ E,      // [64,2304]
                               const float* __restrict__ bhh,
                               const int* __restrict__ paths,
                               const int* __restrict__ src_idx,
                               int* __restrict__ bars)
{
    __shared__ bf16_t whs[96*Dv];        // 147456 B, swizzled 16B chunks
    __shared__ int tok_s[2][192];
    const int tid = threadIdx.x;
    const int s0 = blockIdx.x*192, c0 = blockIdx.y*32;
    const int lane = tid&63, w = tid>>6;
    const int wm = w&3, wn = w>>2;
    const int fr = lane&15, fkq = lane>>4;
    const int ec = c0 + wn*16 + fr;
    int* bar = bars + blockIdx.x*16;

    // one-time: Whh slice -> LDS. local row r = g*32 + cc; chunk c (16B) 0..95.
    for (int idx = tid; idx < 96*96; idx += 512){
        int r = idx/96, c = idx - r*96;
        int grow = (r>>5)*Dv + c0 + (r&31);
        uint4 v = *(const uint4*)&Whh[(size_t)grow*Dv + c*8];
        *(uint4*)&whs[r*Dv + (c ^ (r&15))*8] = v;
    }
    if (tid < 192){
        int s = s0 + tid, b = s/KLv;
        tok_s[0][tid] = paths[(src_idx[b]*KLv + (s - b*KLv))*Pv];
    }
    const float bh_r = bhh[ec], bh_z = bhh[Dv+ec], bh_n = bhh[2*Dv+ec];
    float hp[3][4];
    #pragma unroll
    for (int mt=0;mt<3;mt++){ hp[mt][0]=0.f; hp[mt][1]=0.f; hp[mt][2]=0.f; hp[mt][3]=0.f; }
    __syncthreads();

    for (int t=0; t<Pv; ++t){
        const bf16_t* h_old = (t&1) ? h_b : h_a;
        bf16_t*       h_new = (t&1) ? h_a : h_b;
        f32x4 acc[3][3];
        #pragma unroll
        for (int i=0;i<3;i++)
            #pragma unroll
            for (int j=0;j<3;j++) acc[i][j] = f32x4{0.f,0.f,0.f,0.f};

        const bf16_t* abase = h_old + (size_t)(s0 + wm*48 + fr)*Dv + fkq*8;
        #pragma unroll
        for (int kt=0; kt<24; ++kt){
            bf16x8 a0 = *(const bf16x8*)(abase + kt*32);
            bf16x8 a1 = *(const bf16x8*)(abase + 16*Dv + kt*32);
            bf16x8 a2 = *(const bf16x8*)(abase + 32*Dv + kt*32);
            #pragma unroll
            for (int g=0; g<3; ++g){
                int brow = g*32 + wn*16 + fr;      // brow&15 == fr
                bf16x8 bfr = *(const bf16x8*)&whs[brow*Dv + ((kt*4+fkq) ^ fr)*8];
                acc[0][g] = __builtin_amdgcn_mfma_f32_16x16x32_bf16(a0, bfr, acc[0][g],0,0,0);
                acc[1][g] = __builtin_amdgcn_mfma_f32_16x16x32_bf16(a1, bfr, acc[1][g],0,0,0);
                acc[2][g] = __builtin_amdgcn_mfma_f32_16x16x32_bf16(a2, bfr, acc[2][g],0,0,0);
            }
        }
        // epilogue: gates in registers; h_prev in registers
        #pragma unroll
        for (int mt=0; mt<3; ++mt)
            #pragma unroll
            for (int r4=0; r4<4; ++r4){
                int s = s0 + wm*48 + mt*16 + fkq*4 + r4;
                const float* Erow = E + (size_t)tok_s[t&1][s - s0]*G1v;
                float gr  = Erow[ec]      + acc[mt][0][r4] + bh_r;
                float gz  = Erow[Dv+ec]   + acc[mt][1][r4] + bh_z;
                float gnx = Erow[2*Dv+ec];
                float ghn = acc[mt][2][r4] + bh_n;
                float rg = sigmf(gr), zg = sigmf(gz);
                float ng = tanhft(gnx + rg*ghn);
                float h = (1.f - zg)*ng + zg*hp[mt][r4];
                hp[mt][r4] = h;
                h_new[(size_t)s*Dv + ec] = (bf16_t)h;
            }
        if (t < Pv-1){
            if (tid < 192){
                int s = s0 + tid, b = s/KLv;
                tok_s[(t+1)&1][tid] = paths[(src_idx[b]*KLv + (s - b*KLv))*Pv + (t+1)];
            }
            group_barrier(bar, 24*(t+1));
        }
    }
}

// ---------------------------------------------------------------------------
// Stage-2 persistent bidirectional GRU: batch 192 (bf16 h), hidden 384, 8 steps.
// grid (3,12,2) = 72 blocks; 256 threads (2M x 2N waves); Whh slice
// [96][384] bf16 = 73.7 KB resident. Running max + h_prev in regs.
// ---------------------------------------------------------------------------
__launch_bounds__(256, 2)
__global__ void gru1_seq_kernel(bf16_t* __restrict__ hf_a, bf16_t* __restrict__ hf_b,
                                bf16_t* __restrict__ hb_a, bf16_t* __restrict__ hb_b,
                                const bf16_t* __restrict__ Whf, const bf16_t* __restrict__ Whb,
                                const bf16_t* __restrict__ xg1,
                                const float* __restrict__ bhf, const float* __restrict__ bhb,
                                float* __restrict__ sub, int* __restrict__ bars)
{
    __shared__ bf16_t whs[96*H1v];       // 73728 B
    const int tid = threadIdx.x;
    const int dir = blockIdx.z;
    bf16_t* bufA = dir ? hb_a : hf_a;
    bf16_t* bufB = dir ? hb_b : hf_b;
    const bf16_t* Whh = dir ? Whb : Whf;
    const bf16_t* xg  = xg1 + dir*G2v;
    const float* bhh  = dir ? bhb : bhf;
    int* bar = bars + (8 + dir*3 + blockIdx.x)*16;

    const int s0 = blockIdx.x*64, c0 = blockIdx.y*32;
    const int lane = tid&63, w = tid>>6;
    const int wm = w&1, wn = w>>1;
    const int fr = lane&15, fkq = lane>>4;
    const int ec = c0 + wn*16 + fr;

    for (int idx = tid; idx < 96*48; idx += 256){
        int r = idx/48, c = idx - r*48;
        int grow = (r>>5)*H1v + c0 + (r&31);
        uint4 v = *(const uint4*)&Whh[(size_t)grow*H1v + c*8];
        *(uint4*)&whs[r*H1v + (c ^ (r&15))*8] = v;
    }
    const float bh_r = bhh[ec], bh_z = bhh[H1v+ec], bh_n = bhh[2*H1v+ec];
    float hp[2][4], ym[2][4];
    #pragma unroll
    for (int mt=0;mt<2;mt++){ hp[mt][0]=0.f; hp[mt][1]=0.f; hp[mt][2]=0.f; hp[mt][3]=0.f; }
    __syncthreads();

    for (int t=0; t<Lv; ++t){
        const bf16_t* h_old = (t&1) ? bufB : bufA;
        bf16_t*       h_new = (t&1) ? bufA : bufB;
        const int lidx = dir ? (Lv-1-t) : t;
        f32x4 acc[2][3];
        #pragma unroll
        for (int i=0;i<2;i++)
            #pragma unroll
            for (int j=0;j<3;j++) acc[i][j] = f32x4{0.f,0.f,0.f,0.f};

        const bf16_t* abase = h_old + (size_t)(s0 + wm*32 + fr)*H1v + fkq*8;
        #pragma unroll
        for (int kt=0; kt<12; ++kt){
            bf16x8 a0 = *(const bf16x8*)(abase + kt*32);
            bf16x8 a1 = *(const bf16x8*)(abase + 16*H1v + kt*32);
            #pragma unroll
            for (int g=0; g<3; ++g){
                int brow = g*32 + wn*16 + fr;
                bf16x8 bfr = *(const bf16x8*)&whs[brow*H1v + ((kt*4+fkq) ^ fr)*8];
                acc[0][g] = __builtin_amdgcn_mfma_f32_16x16x32_bf16(a0, bfr, acc[0][g],0,0,0);
                acc[1][g] = __builtin_amdgcn_mfma_f32_16x16x32_bf16(a1, bfr, acc[1][g],0,0,0);
            }
        }
        #pragma unroll
        for (int mt=0; mt<2; ++mt)
            #pragma unroll
            for (int r4=0; r4<4; ++r4){
                int s = s0 + wm*32 + mt*16 + fkq*4 + r4;
                const bf16_t* xrow = xg + (size_t)(s*Lv + lidx)*(2*G2v);
                float gr  = (float)xrow[ec]       + acc[mt][0][r4] + bh_r;
                float gz  = (float)xrow[H1v+ec]   + acc[mt][1][r4] + bh_z;
                float gnx = (float)xrow[2*H1v+ec];
                float ghn = acc[mt][2][r4] + bh_n;
                float rg = sigmf(gr), zg = sigmf(gz);
                float ng = tanhft(gnx + rg*ghn);
                float h = (1.f - zg)*ng + zg*hp[mt][r4];
                hp[mt][r4] = h;
                h_new[(size_t)s*H1v + ec] = (bf16_t)h;
                ym[mt][r4] = (t==0) ? h : fmaxf(ym[mt][r4], h);
            }
        if (t < Lv-1) group_barrier(bar, 12*(t+1));
    }
    #pragma unroll
    for (int mt=0; mt<2; ++mt)
        #pragma unroll
        for (int r4=0; r4<4; ++r4){
            int s = s0 + wm*32 + mt*16 + fkq*4 + r4;
            sub[(size_t)s*Dv + dir*H1v + ec] = fmaxf(ym[mt][r4], 0.f);
        }
}

// ---------------------------------------------------------------------------
// Stage-3 persistent bidirectional LSTM: batch 16 (bf16 h), hidden 384, 12 steps.
// grid (12,2) = 24 blocks; 64 threads (1 wave). Whh slice [128][384] bf16 =
// 98 KB resident. c-state + running max in regs.
// ---------------------------------------------------------------------------
__launch_bounds__(64, 1)
__global__ void lstm_seq_kernel(bf16_t* __restrict__ hf_a, bf16_t* __restrict__ hf_b,
                                bf16_t* __restrict__ hb_a, bf16_t* __restrict__ hb_b,
                                const bf16_t* __restrict__ Wf, const bf16_t* __restrict__ Wb,
                                const bf16_t* __restrict__ xg2,
                                const float* __restrict__ bhf, const float* __restrict__ bhb,
                                float* __restrict__ tempmax, int* __restrict__ bars)
{
    __shared__ bf16_t whs[128*H1v];      // 98304 B
    const int tid = threadIdx.x;
    const int dir = blockIdx.y;
    bf16_t* bufA = dir ? hb_a : hf_a;
    bf16_t* bufB = dir ? hb_b : hf_b;
    const bf16_t* Whh = dir ? Wb : Wf;
    const bf16_t* xg  = xg2 + dir*G3v;
    const float* bhh  = dir ? bhb : bhf;
    int* bar = bars + (14 + dir)*16;
    const int c0 = blockIdx.x*32;
    const int fr = tid&15, fkq = tid>>4;

    for (int idx = tid; idx < 128*48; idx += 64){
        int r = idx/48, c = idx - r*48;
        int grow = (r>>5)*H1v + c0 + (r&31);
        uint4 v = *(const uint4*)&Whh[(size_t)grow*H1v + c*8];
        *(uint4*)&whs[r*H1v + (c ^ (r&15))*8] = v;
    }
    float bh[4][2];
    #pragma unroll
    for (int g=0; g<4; ++g){
        bh[g][0] = bhh[g*H1v + c0 + fr];
        bh[g][1] = bhh[g*H1v + c0 + 16 + fr];
    }
    float cst[2][4], tm[2][4];
    #pragma unroll
    for (int hf=0; hf<2; ++hf){ cst[hf][0]=0.f; cst[hf][1]=0.f; cst[hf][2]=0.f; cst[hf][3]=0.f; }
    __syncthreads();

    for (int t=0; t<Kv; ++t){
        const bf16_t* h_old = (t&1) ? bufB : bufA;
        bf16_t*       h_new = (t&1) ? bufA : bufB;
        const int lidx = dir ? (Kv-1-t) : t;
        f32x4 acc[8];
        #pragma unroll
        for (int i=0;i<8;i++) acc[i] = f32x4{0.f,0.f,0.f,0.f};

        const bf16_t* abase = h_old + (size_t)fr*H1v + fkq*8;
        #pragma unroll
        for (int kt=0; kt<12; ++kt){
            bf16x8 a = *(const bf16x8*)(abase + kt*32);
            #pragma unroll
            for (int nt=0; nt<8; ++nt){
                int brow = nt*16 + fr;
                bf16x8 bfr = *(const bf16x8*)&whs[brow*H1v + ((kt*4+fkq) ^ fr)*8];
                acc[nt] = __builtin_amdgcn_mfma_f32_16x16x32_bf16(a, bfr, acc[nt],0,0,0);
            }
        }
        #pragma unroll
        for (int hf=0; hf<2; ++hf)
            #pragma unroll
            for (int r4=0; r4<4; ++r4){
                int r = fkq*4 + r4;
                int hcol = c0 + hf*16 + fr;
                const bf16_t* xrow = xg + (size_t)(r*Kv + lidx)*(2*G3v);
                float ai = (float)xrow[hcol]        + acc[0+hf][r4] + bh[0][hf];
                float af = (float)xrow[H1v+hcol]    + acc[2+hf][r4] + bh[1][hf];
                float ag = (float)xrow[2*H1v+hcol]  + acc[4+hf][r4] + bh[2][hf];
                float ao = (float)xrow[3*H1v+hcol]  + acc[6+hf][r4] + bh[3][hf];
                float iv = sigmf(ai), fv = sigmf(af), gv = tanhft(ag), ov = sigmf(ao);
                float c = fv*cst[hf][r4] + iv*gv;
                cst[hf][r4] = c;
                float hn = ov*tanhft(c);
                h_new[(size_t)r*H1v + hcol] = (bf16_t)hn;
                tm[hf][r4] = (t==0) ? hn : fmaxf(tm[hf][r4], hn);
            }
        if (t < Kv-1) group_barrier(bar, 12*(t+1));
    }
    #pragma unroll
    for (int hf=0; hf<2; ++hf)
        #pragma unroll
        for (int r4=0; r4<4; ++r4)
            tempmax[(size_t)(fkq*4+r4)*Dv + dir*H1v + c0 + hf*16 + fr] = tm[hf][r4];
}

// ---------------------------------------------------------------------------
// Head kernels (fp32, batch = 16)
// ---------------------------------------------------------------------------
__global__ void bn_kernel(const float* __restrict__ x, const float* __restrict__ g,
                          const float* __restrict__ b, float* __restrict__ y, int Dcols){
    int c = blockIdx.x*256 + threadIdx.x;
    if (c >= Dcols) return;
    float mu = 0.f;
    for (int r=0;r<Bv;r++) mu += x[r*Dcols + c];
    mu *= (1.f/Bv);
    float var = 0.f;
    for (int r=0;r<Bv;r++){ float d = x[r*Dcols + c] - mu; var += d*d; }
    var *= (1.f/Bv);
    float sc = g[c]*rsqrtf(var + 1e-5f);
    for (int r=0;r<Bv;r++) y[r*Dcols + c] = sc*(x[r*Dcols + c] - mu) + b[c];
}

__global__ void out_kernel(const float* __restrict__ A, const float* __restrict__ W,
                           const float* __restrict__ b, float* __restrict__ out){
    int bb = blockIdx.x, lane = threadIdx.x;  // 64 threads
    float s = 0.f;
    for (int k=lane;k<Dv;k+=64) s += A[bb*Dv + k]*W[k];
    #pragma unroll
    for (int off=32;off;off>>=1) s += __shfl_down(s,off);
    if (lane==0) out[bb] = 1.f/(1.f + __expf(-(s + b[0])));
}

// ---------------------------------------------------------------------------
// Launch
// ---------------------------------------------------------------------------
extern "C" void kernel_launch(void* const* d_in, const int* in_sizes, int n_in,
                              void* d_out, int out_size, void* d_ws, size_t ws_size,
                              hipStream_t stream) {
    const float* feature = (const float*)d_in[0];
    const int*   src_idx = (const int*)d_in[1];
    const int*   paths   = (const int*)d_in[2];
    const float* emb     = (const float*)d_in[3];
    const float* gWih    = (const float*)d_in[4];
    const float* gWhh    = (const float*)d_in[5];
    const float* gbih    = (const float*)d_in[6];
    const float* gbhh    = (const float*)d_in[7];
    const float* g1fWih  = (const float*)d_in[8];
    const float* g1fWhh  = (const float*)d_in[9];
    const float* g1fbih  = (const float*)d_in[10];
    const float* g1fbhh  = (const float*)d_in[11];
    const float* g1bWih  = (const float*)d_in[12];
    const float* g1bWhh  = (const float*)d_in[13];
    const float* g1bbih  = (const float*)d_in[14];
    const float* g1bbhh  = (const float*)d_in[15];
    const float* lfWih   = (const float*)d_in[16];
    const float* lfWhh   = (const float*)d_in[17];
    const float* lfbih   = (const float*)d_in[18];
    const float* lfbhh   = (const float*)d_in[19];
    const float* lbWih   = (const float*)d_in[20];
    const float* lbWhh   = (const float*)d_in[21];
    const float* lbbih   = (const float*)d_in[22];
    const float* lbbhh   = (const float*)d_in[23];
    const float* treeW   = (const float*)d_in[24];
    const float* treeb   = (const float*)d_in[25];
    const float* bn1g    = (const float*)d_in[26];
    const float* bn1b    = (const float*)d_in[27];
    const float* bn2g    = (const float*)d_in[28];
    const float* bn2b    = (const float*)d_in[29];
    const float* d1W     = (const float*)d_in[30];
    const float* d1b     = (const float*)d_in[31];
    const float* d2W     = (const float*)d_in[32];
    const float* d2b     = (const float*)d_in[33];
    const float* outW    = (const float*)d_in[34];
    const float* outb    = (const float*)d_in[35];
    float* out = (float*)d_out;

    // ---- workspace (~26 MB, the r2/r3-passing footprint class) ----
    char* ws = (char*)d_ws;
    size_t off = 0;
    auto alloc = [&](size_t bytes)->char*{
        char* p = ws + off;
        off += (bytes + 255) & ~(size_t)255;
        return p;
    };
    float*  E      = (float*)alloc((size_t)64*G1v*4);          // 589,824
    char*   Wreg   = alloc(4718592);                           // time-shared weight scratch
    float*  emb_pad= (float*)alloc((size_t)64*Dv*4);
    bf16_t* h_a    = (bf16_t*)alloc((size_t)N1v*Dv*2);         // bf16 h; phase4: lW casts
    bf16_t* h_b    = (bf16_t*)alloc((size_t)N1v*Dv*2);
    float*  leafs  = (float*)alloc((size_t)N1v*Dv*4);
    bf16_t* xg1    = (bf16_t*)alloc((size_t)N1v*2*G2v*2);      // [1536][2304]
    bf16_t* xg2    = (bf16_t*)alloc((size_t)BKv*2*G3v*2);      // [192][3072]
    bf16_t* h1f_a  = (bf16_t*)alloc((size_t)BKv*H1v*2);
    bf16_t* h1f_b  = (bf16_t*)alloc((size_t)BKv*H1v*2);
    bf16_t* h1b_a  = (bf16_t*)alloc((size_t)BKv*H1v*2);
    bf16_t* h1b_b  = (bf16_t*)alloc((size_t)BKv*H1v*2);
    float*  sub    = (float*)alloc((size_t)BKv*Dv*4);
    bf16_t* lhf_a  = (bf16_t*)alloc((size_t)Bv*H1v*2);
    bf16_t* lhf_b  = (bf16_t*)alloc((size_t)Bv*H1v*2);
    bf16_t* lhb_a  = (bf16_t*)alloc((size_t)Bv*H1v*2);
    bf16_t* lhb_b  = (bf16_t*)alloc((size_t)Bv*H1v*2);
    float*  tempmax= (float*)alloc((size_t)Bv*Dv*4);
    float*  hb1    = (float*)alloc((size_t)64*Dv*4);
    float*  hd1    = (float*)alloc((size_t)64*G3v*4);
    float*  hb2    = (float*)alloc((size_t)64*G3v*4);
    float*  hd2    = (float*)alloc((size_t)64*Dv*4);
    float*  bias1  = (float*)alloc((size_t)2*G2v*4);
    float*  bias2  = (float*)alloc((size_t)2*G3v*4);
    int*    bars   = (int*)alloc(1024);                        // 16 counters x 64B
    (void)ws_size; (void)in_sizes; (void)n_in; (void)out_size;

    // time-shared aliases inside Wreg (stream order serializes phases)
    bf16_t* gWih_bf  = (bf16_t*)Wreg;                          // phase 1a
    bf16_t* Whh_bf   = (bf16_t*)Wreg;                          // phase 1b (after E-GEMM)
    bf16_t* treeW_bf = (bf16_t*)Wreg;                          // phase 2
    bf16_t* w1fb_bf  = (bf16_t*)(Wreg + 1179648);              // [2304][768]
    bf16_t* u1f_bf   = (bf16_t*)Wreg;                          // phase 3
    bf16_t* u1b_bf   = (bf16_t*)(Wreg + 884736);
    bf16_t* lwfb_bf  = (bf16_t*)Wreg;                          // phase 4: [3072][768]
    bf16_t* lWf_bf   = (bf16_t*)h_a;                           // phase 4: h_a dead
    bf16_t* lWb_bf   = (bf16_t*)((char*)h_a + 1179648);
    bf16_t* d1W_bf   = (bf16_t*)Wreg;                          // phase 5
    bf16_t* d2W_bf   = (bf16_t*)(Wreg + 2359296);

    auto mcast = [&](CastSeg a, CastSeg b, CastSeg c, CastSeg d){
        int total4 = a.n4 + b.n4 + c.n4 + d.n4;
        mcast_kernel<<<(total4+255)/256, 256, 0, stream>>>(a, b, c, d, total4);
    };
    CastSeg nil{nullptr,nullptr,0};

    // ---- init (ws is re-poisoned before every call) ----
    hipMemsetAsync(bars, 0, 1024, stream);
    hipMemsetAsync(emb_pad, 0, (size_t)64*Dv*4, stream);
    hipMemsetAsync(h_a,   0, (size_t)N1v*Dv*2, stream);
    hipMemsetAsync(h1f_a, 0, (size_t)BKv*H1v*2, stream);
    hipMemsetAsync(h1b_a, 0, (size_t)BKv*H1v*2, stream);
    hipMemsetAsync(lhf_a, 0, (size_t)Bv*H1v*2, stream);
    hipMemsetAsync(lhb_a, 0, (size_t)Bv*H1v*2, stream);
    hipMemsetAsync(hb1,   0, (size_t)64*Dv*4, stream);
    hipMemsetAsync(hb2,   0, (size_t)64*G3v*4, stream);
    hipMemcpyAsync(emb_pad, emb, (size_t)Vv*Dv*4, hipMemcpyDeviceToDevice, stream);
    hipMemcpyAsync(bias1,       g1fbih, G2v*4, hipMemcpyDeviceToDevice, stream);
    hipMemcpyAsync(bias1+G2v,   g1bbih, G2v*4, hipMemcpyDeviceToDevice, stream);
    hipMemcpyAsync(bias2,       lfbih,  G3v*4, hipMemcpyDeviceToDevice, stream);
    hipMemcpyAsync(bias2+G3v,   lbbih,  G3v*4, hipMemcpyDeviceToDevice, stream);

    // ---- phase 1: E = emb @ gWih^T + gbih, then stage-1 persistent GRU ----
    mcast({gWih, gWih_bf, G1v*Dv/4}, nil, nil, nil);
    gemm_bt_kernel<float,float,false><<<dim3(1, G1v/64), 256, 0, stream>>>(emb_pad, gWih_bf, gbih, (const float*)nullptr, E, G1v, Dv);
    mcast({gWhh, Whh_bf, G1v*Dv/4}, nil, nil, nil);   // aliases gWih_bf; after E-GEMM
    gru_seq_kernel<<<dim3(N1v/192, Dv/32), 512, 0, stream>>>(h_a, h_b, Whh_bf, E, gbhh, paths, src_idx, bars);

    // ---- phase 2: leafs (+bf16 h add) + stage-2 input projection (merged dirs) ----
    mcast({treeW, treeW_bf, Dv*Dv/4}, {g1fWih, w1fb_bf, G2v*Dv/4},
          {g1bWih, w1fb_bf + (size_t)G2v*Dv, G2v*Dv/4}, nil);
    gemm_bt_kernel<float,bf16_t,false><<<dim3(N1v/64, Dv/64), 256, 0, stream>>>(feature, treeW_bf, treeb, h_a, leafs, Dv, Dv);
    gemm_bt_kernel<bf16_t,float,false><<<dim3(N1v/64, 2*G2v/64), 256, 0, stream>>>(leafs, w1fb_bf, bias1, (const float*)nullptr, xg1, 2*G2v, Dv);

    // ---- phase 3: stage-2 persistent bidirectional GRU (writes sub) ----
    mcast({g1fWhh, u1f_bf, G2v*H1v/4}, {g1bWhh, u1b_bf, G2v*H1v/4}, nil, nil);
    gru1_seq_kernel<<<dim3(BKv/64, H1v/32, 2), 256, 0, stream>>>(
        h1f_a, h1f_b, h1b_a, h1b_b, u1f_bf, u1b_bf, xg1, g1fbhh, g1bbhh, sub, bars);

    // ---- phase 4: stage-3 input projection + persistent LSTM ----
    mcast({lfWih, lwfb_bf, G3v*Dv/4}, {lbWih, lwfb_bf + (size_t)G3v*Dv, G3v*Dv/4},
          {lfWhh, lWf_bf, G3v*H1v/4}, {lbWhh, lWb_bf, G3v*H1v/4});
    gemm_bt_kernel<bf16_t,float,false><<<dim3(BKv/64, 2*G3v/64), 256, 0, stream>>>(sub, lwfb_bf, bias2, (const float*)nullptr, xg2, 2*G3v, Dv);
    lstm_seq_kernel<<<dim3(H1v/32, 2), 64, 0, stream>>>(
        lhf_a, lhf_b, lhb_a, lhb_b, lWf_bf, lWb_bf, xg2, lfbhh, lbbhh, tempmax, bars);

    // ---- phase 5: head (M padded to 64; pad rows zeroed each call) ----
    mcast({d1W, d1W_bf, G3v*Dv/4}, {d2W, d2W_bf, Dv*G3v/4}, nil, nil);
    bn_kernel<<<(Dv+255)/256, 256, 0, stream>>>(tempmax, bn1g, bn1b, hb1, Dv);
    gemm_bt_kernel<float,float,true><<<dim3(1, G3v/64), 256, 0, stream>>>(hb1, d1W_bf, d1b, (const float*)nullptr, hd1, G3v, Dv);
    bn_kernel<<<(G3v+255)/256, 256, 0, stream>>>(hd1, bn2g, bn2b, hb2, G3v);
    gemm_bt_kernel<float,float,true><<<dim3(1, Dv/64), 256, 0, stream>>>(hb2, d2W_bf, d2b, (const float*)nullptr, hd2, Dv, G3v);
    out_kernel<<<Bv, 64, 0, stream>>>(hd2, outW, outb, out);
}